// Round 10
// baseline (244.532 us; speedup 1.0000x reference)
//
#include <hip/hip_runtime.h>
#include <math.h>

// MultiHeadBigBirdAttention: B=2, S=2048, E=1024, H=8, DH=128
// Pipeline (bf16 MFMA 16x16x32):
//   1. prep: fused {q,k,v fp32->bf16} + {W* fp32 [K][N] -> bf16 W^T [N][K]}
//   2. gemm_qkv (grid 32x8x3): projections -> Qh/Kh [B,H,S,DH], Vt [B,H,DH,S]
//   3. flash_k: static-max flash v9b -> ctx bf16
//   4. gemm_out (grid 64x8): ctx @ Wo^T + bo -> d_out fp32, BM=64 tile
//
// MFMA layouts (verified learn_hip m89/m91/m120):
//   C/D: col = lane&15, row = (lane>>4)*4 + reg
//   A:   m   = lane&15, k   = (lane>>4)*8 + j
//   B:   n   = lane&15, k   = (lane>>4)*8 + j
//
// R18: flash v9b = R17 structure with the launch_bounds cap REMOVED.
// R17 postmortem: __launch_bounds__(...,4) made hipcc clamp to 64 VGPR
// against ~115 demand (same trap as R14) -> spill (WRITE_SIZE +2MB, dur
// 75us). The v9 mechanism itself was validated: occupancy hit 28%, FETCH
// ~12.8MB (V direct-from-global is L2-resident). With plain
// __launch_bounds__(512) the allocator should settle ~110-125 VGPR ->
// floor(512/VGPR)=4 waves/SIMD -> 16 waves/CU = 2 blocks/CU (LDS 43KB)
// = the target TLP without spill.
// JOURNAL RULE: never pass a second launch_bounds arg on these flash
// kernels — hipcc jumps to the 64-VGPR tier and spills.

typedef __bf16 bf16_t;
typedef __bf16 bf16x8 __attribute__((ext_vector_type(8)));
typedef float f32x4 __attribute__((ext_vector_type(4)));

#define MFMA16(a, b, c) __builtin_amdgcn_mfma_f32_16x16x32_bf16(a, b, c, 0, 0, 0)

// ---------------------------------------------------------------------------
// prep: blocks 0..6143 convert q/k/v fp32->bf16 (8 elems/thread);
//       blocks 6144..10239 transpose the 4 weight matrices to bf16 W^T.
// ---------------------------------------------------------------------------
__global__ __launch_bounds__(256) void prep(const float* q, const float* k,
                                            const float* v, bf16_t* qb,
                                            bf16_t* kb, bf16_t* vb,
                                            const float* W0, const float* W1,
                                            const float* W2, const float* W3,
                                            bf16_t* Wt) {
  const int bid = blockIdx.x, tid = threadIdx.x;
  if (bid < 6144) {
    const int z = bid >> 11, chunk = bid & 2047;
    const float* x = (z == 0) ? q : (z == 1) ? k : v;
    bf16_t* y = (z == 0) ? qb : (z == 1) ? kb : vb;
    size_t i = ((size_t)chunk * 256 + tid) * 8;
    float4 a = *(const float4*)(x + i);
    float4 b = *(const float4*)(x + i + 4);
    bf16x8 o = {(bf16_t)a.x, (bf16_t)a.y, (bf16_t)a.z, (bf16_t)a.w,
                (bf16_t)b.x, (bf16_t)b.y, (bf16_t)b.z, (bf16_t)b.w};
    *(bf16x8*)(y + i) = o;
  } else {
    __shared__ float t[32][33];
    const int b2 = bid - 6144;
    const int wz = b2 >> 10, t2 = b2 & 1023;
    const float* W = (wz == 0) ? W0 : (wz == 1) ? W1 : (wz == 2) ? W2 : W3;
    bf16_t* o = Wt + (size_t)wz * 1024 * 1024;
    const int n0 = (t2 & 31) * 32, k0 = (t2 >> 5) * 32;
    const int tx = tid & 31, ty = tid >> 5;
#pragma unroll
    for (int i = 0; i < 4; i++)
      t[ty + 8 * i][tx] = W[(size_t)(k0 + ty + 8 * i) * 1024 + n0 + tx];
    __syncthreads();
#pragma unroll
    for (int i = 0; i < 4; i++)
      o[(size_t)(n0 + ty + 8 * i) * 1024 + k0 + tx] = (bf16_t)t[tx][ty + 8 * i];
  }
}

// ---------------------------------------------------------------------------
// gemm_qkv: 128x128 tile, BK=64, LDS double-buffered, register-staged
// pipeline (R8 skeleton, proven). Grid (bm=32, bn=8, z=3) -> XCD = bm%8;
// per-XCD L2 working set = 4 A-tiles (1MB) + W^T (2MB).
// ---------------------------------------------------------------------------
__global__ __launch_bounds__(256) void gemm_qkv(
    const bf16_t* qb, const bf16_t* kb, const bf16_t* vb, const bf16_t* Wt,
    const float* b0, const float* b1, const float* b2, bf16_t* Qh, bf16_t* Kh,
    bf16_t* Vt) {
  __shared__ bf16_t As[2][128 * 64];
  __shared__ bf16_t Bs[2][128 * 64];
  const int tid = threadIdx.x, w = tid >> 6, lane = tid & 63;
  const int bm = blockIdx.x, bn = blockIdx.y;  // XCD = bm%8
  const int wr = w >> 1, wc = w & 1, q4 = lane >> 4, lo = lane & 15;
  const int z = blockIdx.z;
  const bf16_t* A = (z == 0) ? qb : (z == 1) ? kb : vb;
  const bf16_t* Bt = Wt + (size_t)z * 1024 * 1024;
  const float* bias = (z == 0) ? b0 : (z == 1) ? b1 : b2;

  f32x4 acc[4][4];
#pragma unroll
  for (int m = 0; m < 4; m++)
#pragma unroll
    for (int n = 0; n < 4; n++) acc[m][n] = (f32x4){0.f, 0.f, 0.f, 0.f};

  const int r2 = tid >> 1;         // 0..127
  const int cb = (tid & 1) * 4;    // chunk base 0 / 4
  const bf16_t* Arow = A + (size_t)(bm * 128 + r2) * 1024;
  const bf16_t* Brow = Bt + (size_t)(bn * 128 + r2) * 1024;

  bf16x8 ar[4], br[4];
  auto loadAB = [&](int k0) {
#pragma unroll
    for (int i = 0; i < 4; i++) {
      ar[i] = *(const bf16x8*)(Arow + k0 + (cb + i) * 8);
      br[i] = *(const bf16x8*)(Brow + k0 + (cb + i) * 8);
    }
  };

  loadAB(0);
  for (int k = 0; k < 16; k++) {
    const int cur = k & 1;
    // deposit tile k (waits only on its own global loads)
#pragma unroll
    for (int i = 0; i < 4; i++) {
      *(bf16x8*)&As[cur][r2 * 64 + (((cb + i) ^ (r2 & 7)) * 8)] = ar[i];
      *(bf16x8*)&Bs[cur][r2 * 64 + (((cb + i) ^ (r2 & 7)) * 8)] = br[i];
    }
    // prefetch tile k+1 into private regs (in flight through barrier+compute)
    if (k < 15) loadAB((k + 1) * 64);
    __syncthreads();

#pragma unroll
    for (int kc = 0; kc < 2; kc++) {
      bf16x8 af[4], bfr[4];
#pragma unroll
      for (int m = 0; m < 4; m++) {
        int rr = wr * 64 + m * 16 + lo;
        af[m] = *(const bf16x8*)&As[cur][rr * 64 + (((kc * 4 + q4) ^ (rr & 7)) * 8)];
      }
#pragma unroll
      for (int n = 0; n < 4; n++) {
        int rr = wc * 64 + n * 16 + lo;
        bfr[n] = *(const bf16x8*)&Bs[cur][rr * 64 + (((kc * 4 + q4) ^ (rr & 7)) * 8)];
      }
#pragma unroll
      for (int m = 0; m < 4; m++)
#pragma unroll
        for (int n = 0; n < 4; n++)
          acc[m][n] = MFMA16(af[m], bfr[n], acc[m][n]);
    }
    // no trailing barrier: dbuf + top-of-iter deposit make it safe
  }

#pragma unroll
  for (int m = 0; m < 4; m++) {
#pragma unroll
    for (int n = 0; n < 4; n++) {
      int rowg0 = bm * 128 + wr * 64 + m * 16 + q4 * 4;
      int colg = bn * 128 + wc * 64 + n * 16 + lo;
      float bv = bias[colg];
#pragma unroll
      for (int rg = 0; rg < 4; rg++) {
        float val = acc[m][n][rg] + bv;
        int row = rowg0 + rg;
        int b = row >> 11, s = row & 2047;  // S=2048
        int h = colg >> 7, d = colg & 127;  // DH=128
        if (z == 0)
          Qh[(((size_t)(b * 8 + h)) * 2048 + s) * 128 + d] = (bf16_t)val;
        else if (z == 1)
          Kh[(((size_t)(b * 8 + h)) * 2048 + s) * 128 + d] = (bf16_t)val;
        else
          Vt[(((size_t)(b * 8 + h)) * 128 + d) * 2048 + s] = (bf16_t)val;
      }
    }
  }
}

// ---------------------------------------------------------------------------
// gemm_out: BM=64 x BN=128 tile, BK=64. Grid (64, 8) = 512 blocks = 2/CU.
// 4 waves as 2x2: wave (wr,wc) computes rows wr*32..+31 x cols wc*64..+63.
// Same reg-staged dbuf skeleton and XOR-swizzle family as gemm_qkv.
// ---------------------------------------------------------------------------
__global__ __launch_bounds__(256) void gemm_out(const bf16_t* ctx,
                                                const bf16_t* Wt3,
                                                const float* bo, float* Of32) {
  __shared__ bf16_t As[2][64 * 64];
  __shared__ bf16_t Bs[2][128 * 64];
  const int tid = threadIdx.x, w = tid >> 6, lane = tid & 63;
  const int bm = blockIdx.x, bn = blockIdx.y;  // XCD = bm%8
  const int wr = w >> 1, wc = w & 1, q4 = lane >> 4, lo = lane & 15;

  f32x4 acc[2][4];
#pragma unroll
  for (int m = 0; m < 2; m++)
#pragma unroll
    for (int n = 0; n < 4; n++) acc[m][n] = (f32x4){0.f, 0.f, 0.f, 0.f};

  const int r2a = tid >> 2;        // 0..63
  const int cba = (tid & 3) * 2;   // chunk base 0/2/4/6
  const int r2b = tid >> 1;        // 0..127
  const int cbb = (tid & 1) * 4;   // chunk base 0/4
  const bf16_t* Arow = ctx + (size_t)(bm * 64 + r2a) * 1024;
  const bf16_t* Brow = Wt3 + (size_t)(bn * 128 + r2b) * 1024;

  bf16x8 ar[2], br[4];
  auto loadAB = [&](int k0) {
#pragma unroll
    for (int i = 0; i < 2; i++)
      ar[i] = *(const bf16x8*)(Arow + k0 + (cba + i) * 8);
#pragma unroll
    for (int i = 0; i < 4; i++)
      br[i] = *(const bf16x8*)(Brow + k0 + (cbb + i) * 8);
  };

  loadAB(0);
  for (int k = 0; k < 16; k++) {
    const int cur = k & 1;
#pragma unroll
    for (int i = 0; i < 2; i++)
      *(bf16x8*)&As[cur][r2a * 64 + (((cba + i) ^ (r2a & 7)) * 8)] = ar[i];
#pragma unroll
    for (int i = 0; i < 4; i++)
      *(bf16x8*)&Bs[cur][r2b * 64 + (((cbb + i) ^ (r2b & 7)) * 8)] = br[i];
    if (k < 15) loadAB((k + 1) * 64);
    __syncthreads();

#pragma unroll
    for (int kc = 0; kc < 2; kc++) {
      bf16x8 af[2], bfr[4];
#pragma unroll
      for (int m = 0; m < 2; m++) {
        int rr = wr * 32 + m * 16 + lo;
        af[m] = *(const bf16x8*)&As[cur][rr * 64 + (((kc * 4 + q4) ^ (rr & 7)) * 8)];
      }
#pragma unroll
      for (int n = 0; n < 4; n++) {
        int rr = wc * 64 + n * 16 + lo;
        bfr[n] = *(const bf16x8*)&Bs[cur][rr * 64 + (((kc * 4 + q4) ^ (rr & 7)) * 8)];
      }
#pragma unroll
      for (int m = 0; m < 2; m++)
#pragma unroll
        for (int n = 0; n < 4; n++)
          acc[m][n] = MFMA16(af[m], bfr[n], acc[m][n]);
    }
  }

#pragma unroll
  for (int m = 0; m < 2; m++) {
#pragma unroll
    for (int n = 0; n < 4; n++) {
      int rowg0 = bm * 64 + wr * 32 + m * 16 + q4 * 4;
      int colg = bn * 128 + wc * 64 + n * 16 + lo;
      float bv = bo[colg];
#pragma unroll
      for (int rg = 0; rg < 4; rg++)
        Of32[(size_t)(rowg0 + rg) * 1024 + colg] = acc[m][n][rg] + bv;
    }
  }
}

// ---------------------------------------------------------------------------
// Flash attention v9b: 512 blocks (t/(31-t) pairing) x 512 threads.
// Wave (r=w>>1, kh=w&1) owns rows r*16..+15 x keys kh*32..+31 of the 64-row
// Q tile. K reg-staged dbuf LDS (R8 skeleton); V direct global->reg (each
// wave needs only chunk q4 of key-half kh per V row: 8 bf16x8). P wave-
// private [16][40]. LDS 43KB; natural VGPR (~115) -> 4 waves/SIMD,
// 2 blocks/CU. NO second launch_bounds arg (R14/R17: it forces VGPR=64
// -> spill). Key-half partials combined once at end via dead K-dbuf arena.
// ---------------------------------------------------------------------------
__global__ __launch_bounds__(512) void flash_k(const bf16_t* Qh,
                                               const bf16_t* Kh,
                                               const bf16_t* Vt, bf16_t* ctx,
                                               const int* causal_p) {
  __shared__ bf16_t sm[16384 + 8 * 640];  // K dbuf 32KB + P 10KB
  const int tid = threadIdx.x, w = tid >> 6, lane = tid & 63;
  const int q4 = lane >> 4, lo = lane & 15;
  const int r = w >> 1, kh = w & 1;  // row-group (16 rows), key-half (32 keys)
  const int n0 = blockIdx.x;
  const int u = n0 & 255, hi = n0 >> 8;
  const int bh = u & 15, p0 = u >> 4;
  const int t = hi ? (31 - p0) : p0;
  const int causal = *causal_p;
  const int kmax = causal ? t : 31;

  bf16_t* Ps = sm + 16384 + w * 640;  // [16 rows][40]

  // Q fragments: rows t*64 + r*16 + lo, dh chunk ks*32 + q4*8.
  bf16x8 aq[4];
  {
    const bf16_t* qa =
        Qh + ((size_t)bh * 2048 + t * 64 + r * 16 + lo) * 128;
#pragma unroll
    for (int ks = 0; ks < 4; ks++)
      aq[ks] = *(const bf16x8*)(qa + ks * 32 + q4 * 8);
  }

  const bf16_t* Kbase = Kh + (size_t)bh * 2048 * 128;
  // V B-fragment base: row d = n*16+lo, keys kt*64 + kh*32 + q4*8..+7.
  const bf16_t* Vb = Vt + ((size_t)bh * 128 + lo) * 2048 + kh * 32 + q4 * 8;
  const int kr = tid >> 3, kc = (tid & 7) * 2;  // K staging: 2 chunks/thread

  bf16x8 kreg[2], vreg[8];
  auto loadK = [&](int kt) {
    const bf16_t* kp = Kbase + (size_t)(kt * 64 + kr) * 128;
#pragma unroll
    for (int i = 0; i < 2; i++) kreg[i] = *(const bf16x8*)(kp + (kc + i) * 8);
  };
  auto loadV = [&](int kt) {
#pragma unroll
    for (int n = 0; n < 8; n++)
      vreg[n] = *(const bf16x8*)(Vb + (size_t)n * (16 * 2048) + kt * 64);
  };

  f32x4 acc[8], lacc;
#pragma unroll
  for (int i = 0; i < 8; i++) acc[i] = (f32x4){0.f, 0.f, 0.f, 0.f};
  lacc = (f32x4){0.f, 0.f, 0.f, 0.f};

  const bf16_t one = (bf16_t)1.0f;
  const bf16x8 vone = {one, one, one, one, one, one, one, one};
  const float sc2 = 0.08838834764831845f * 1.44269504088896f;

  loadK(0);
  for (int kt = 0; kt <= kmax; ++kt) {
    bf16_t* Kd = sm + (kt & 1) * 8192;
    // deposit K tile kt (waits only on its own global loads)
#pragma unroll
    for (int i = 0; i < 2; i++)
      *(bf16x8*)&Kd[kr * 128 + (((kc + i) ^ (kr & 7)) * 8)] = kreg[i];
    if (kt < kmax) loadK(kt + 1);  // in flight through barrier+compute
    loadV(kt);                     // consumed at PV (~QK^T+softmax of cover)
    __syncthreads();

    // ---- QK^T: [16 rows x 32 keys] per wave ----
    f32x4 sa[2];
#pragma unroll
    for (int nt = 0; nt < 2; nt++) sa[nt] = (f32x4){0.f, 0.f, 0.f, 0.f};
#pragma unroll
    for (int ks = 0; ks < 4; ks++) {
#pragma unroll
      for (int nt = 0; nt < 2; nt++) {
        int key = kh * 32 + nt * 16 + lo;
        bf16x8 bk =
            *(const bf16x8*)&Kd[key * 128 + (((ks * 4 + q4) ^ (key & 7)) * 8)];
        sa[nt] = MFMA16(aq[ks], bk, sa[nt]);
      }
    }

    // ---- softmax numerator -> wave-private P [16 rows x 32 keys] ----
    const bool diag = causal && (kt == t);
#pragma unroll
    for (int nt = 0; nt < 2; nt++) {
      int keyrel = kh * 32 + nt * 16 + lo;  // within 64-key tile
#pragma unroll
      for (int rg = 0; rg < 4; rg++) {
        int rowrel = r * 16 + q4 * 4 + rg;
        float pv = exp2f(sa[nt][rg] * sc2);
        if (diag && keyrel > rowrel) pv = 0.f;
        Ps[(q4 * 4 + rg) * 40 + nt * 16 + lo] = (bf16_t)pv;
      }
    }

    // ---- P fragment (K=32 = wave's whole key-half), row-sum, PV ----
    bf16x8 ap = *(const bf16x8*)&Ps[lo * 40 + q4 * 8];
    lacc = MFMA16(ap, vone, lacc);
#pragma unroll
    for (int n = 0; n < 8; n++) acc[n] = MFMA16(ap, vreg[n], acc[n]);
  }

  // ---- combine key-half partials (once per block) ----
  __syncthreads();  // K dbuf now dead; all Ps reads done
  float* farena = (float*)sm;  // 8192 floats = 32KB (K dbuf region)
  if (kh == 1) {
    int base = r * 2048 + lane * 32;
#pragma unroll
    for (int n = 0; n < 8; n++)
      *(f32x4*)&farena[base + ((n ^ (lane & 7)) & 7) * 4] = acc[n];
    float* lp = (float*)(sm + 16384 + w * 640);
    *(f32x4*)&lp[lane * 4] = lacc;
  }
  __syncthreads();
  if (kh == 0) {
    int base = r * 2048 + lane * 32;
    float* lp = (float*)(sm + 16384 + (w + 1) * 640);
    lacc += *(const f32x4*)&lp[lane * 4];
#pragma unroll
    for (int n = 0; n < 8; n++)
      acc[n] += *(const f32x4*)&farena[base + ((n ^ (lane & 7)) & 7) * 4];
    int b = bh >> 3, h = bh & 7;
#pragma unroll
    for (int rg = 0; rg < 4; rg++) {
      float inv = 1.f / lacc[rg];
      int row = b * 2048 + t * 64 + r * 16 + q4 * 4 + rg;
#pragma unroll
      for (int n = 0; n < 8; n++)
        ctx[(size_t)row * 1024 + h * 128 + n * 16 + lo] =
            (bf16_t)(acc[n][rg] * inv);
    }
  }
}

// ---------------------------------------------------------------------------
extern "C" void kernel_launch(void* const* d_in, const int* in_sizes, int n_in,
                              void* d_out, int out_size, void* d_ws,
                              size_t ws_size, hipStream_t stream) {
  const float* q = (const float*)d_in[0];
  const float* k = (const float*)d_in[1];
  const float* v = (const float*)d_in[2];
  const float* Wq = (const float*)d_in[3];
  const float* bq = (const float*)d_in[4];
  const float* Wk = (const float*)d_in[5];
  const float* bk = (const float*)d_in[6];
  const float* Wv = (const float*)d_in[7];
  const float* bv = (const float*)d_in[8];
  const float* Wo = (const float*)d_in[9];
  const float* bo = (const float*)d_in[10];
  const int* isc = (const int*)d_in[11];

  char* ws = (char*)d_ws;
  bf16_t* Wt = (bf16_t*)ws;                     // 8MB: W^T bf16 x4
  bf16_t* qb = (bf16_t*)(ws + (8ull << 20));    // 8MB
  bf16_t* kb = (bf16_t*)(ws + (16ull << 20));   // 8MB
  bf16_t* vb = (bf16_t*)(ws + (24ull << 20));   // 8MB
  bf16_t* Qh = (bf16_t*)(ws + (32ull << 20));   // 8MB [B,H,S,DH]
  bf16_t* Kh = (bf16_t*)(ws + (40ull << 20));   // 8MB [B,H,S,DH]
  bf16_t* Vt = (bf16_t*)(ws + (48ull << 20));   // 8MB [B,H,DH,S]
  bf16_t* ctx = (bf16_t*)(ws + (8ull << 20));   // reuse qb

  prep<<<dim3(10240), 256, 0, stream>>>(q, k, v, qb, kb, vb, Wq, Wk, Wv, Wo, Wt);

  gemm_qkv<<<dim3(32, 8, 3), 256, 0, stream>>>(qb, kb, vb, Wt, bq, bk, bv, Qh,
                                               Kh, Vt);

  flash_k<<<dim3(512), 512, 0, stream>>>(Qh, Kh, Vt, ctx, isc);

  gemm_out<<<dim3(64, 8), 256, 0, stream>>>(ctx, Wt + 3ull * 1024 * 1024, bo,
                                            (float*)d_out);
}

// Round 11
// 228.022 us; speedup vs baseline: 1.0724x; 1.0724x over previous
//
#include <hip/hip_runtime.h>
#include <math.h>

// MultiHeadBigBirdAttention: B=2, S=2048, E=1024, H=8, DH=128
// Pipeline (bf16 MFMA 16x16x32):
//   1. prep: fused {q,k,v fp32->bf16} + {W* fp32 [K][N] -> bf16 W^T [N][K]}
//   2. gemm_qkv (grid 32x8x3, BK=32): projections -> Qh/Kh, Vt
//   3. flash_k: static-max flash (R13 structure, 51.5us proven) -> ctx bf16
//   4. gemm_out (grid 64x8, BK=32): ctx @ Wo^T + bo -> d_out fp32
//
// MFMA layouts (verified learn_hip m89/m91/m120):
//   C/D: col = lane&15, row = (lane>>4)*4 + reg
//   A:   m   = lane&15, k   = (lane>>4)*8 + j
//   B:   n   = lane&15, k   = (lane>>4)*8 + j
//
// R19:
//   - flash: REVERT to R13 exactly. R18 postmortem: hipcc gives 512-thread
//     blocks only 68 VGPR (vs 108 at 256 threads) -> V loads sunk to use
//     point -> exposed latency. Wave-geometry path to >2 waves/SIMD is
//     closed; flash stays at its 51.5us structure.
//   - gemms: BK 64->32. They are latency-bound (MfmaUtil 16%) and LDS-
//     capped at 2 blocks/CU; gemm_qkv's 768 blocks over a 2-resident cap
//     forced a 3rd scheduling round. BK=32 halves LDS (qkv 32KB, out 24KB)
//     -> 3-5 blocks/CU resident, same total loads/MFMA, prefetch slack
//     still one full iter. Chunk-XOR swizzle shrinks to 4-space (^row&3,
//     worst 2-way aliasing = free per m136).

typedef __bf16 bf16_t;
typedef __bf16 bf16x8 __attribute__((ext_vector_type(8)));
typedef float f32x4 __attribute__((ext_vector_type(4)));

#define MFMA16(a, b, c) __builtin_amdgcn_mfma_f32_16x16x32_bf16(a, b, c, 0, 0, 0)

// ---------------------------------------------------------------------------
// prep: blocks 0..6143 convert q/k/v fp32->bf16 (8 elems/thread);
//       blocks 6144..10239 transpose the 4 weight matrices to bf16 W^T.
// ---------------------------------------------------------------------------
__global__ __launch_bounds__(256) void prep(const float* q, const float* k,
                                            const float* v, bf16_t* qb,
                                            bf16_t* kb, bf16_t* vb,
                                            const float* W0, const float* W1,
                                            const float* W2, const float* W3,
                                            bf16_t* Wt) {
  const int bid = blockIdx.x, tid = threadIdx.x;
  if (bid < 6144) {
    const int z = bid >> 11, chunk = bid & 2047;
    const float* x = (z == 0) ? q : (z == 1) ? k : v;
    bf16_t* y = (z == 0) ? qb : (z == 1) ? kb : vb;
    size_t i = ((size_t)chunk * 256 + tid) * 8;
    float4 a = *(const float4*)(x + i);
    float4 b = *(const float4*)(x + i + 4);
    bf16x8 o = {(bf16_t)a.x, (bf16_t)a.y, (bf16_t)a.z, (bf16_t)a.w,
                (bf16_t)b.x, (bf16_t)b.y, (bf16_t)b.z, (bf16_t)b.w};
    *(bf16x8*)(y + i) = o;
  } else {
    __shared__ float t[32][33];
    const int b2 = bid - 6144;
    const int wz = b2 >> 10, t2 = b2 & 1023;
    const float* W = (wz == 0) ? W0 : (wz == 1) ? W1 : (wz == 2) ? W2 : W3;
    bf16_t* o = Wt + (size_t)wz * 1024 * 1024;
    const int n0 = (t2 & 31) * 32, k0 = (t2 >> 5) * 32;
    const int tx = tid & 31, ty = tid >> 5;
#pragma unroll
    for (int i = 0; i < 4; i++)
      t[ty + 8 * i][tx] = W[(size_t)(k0 + ty + 8 * i) * 1024 + n0 + tx];
    __syncthreads();
#pragma unroll
    for (int i = 0; i < 4; i++)
      o[(size_t)(n0 + ty + 8 * i) * 1024 + k0 + tx] = (bf16_t)t[tx][ty + 8 * i];
  }
}

// ---------------------------------------------------------------------------
// gemm_qkv: 128x128 tile, BK=32, LDS double-buffered (2x8KB per matrix =
// 32KB total -> 3+ blocks/CU), register-staged pipeline (R8 skeleton).
// Staging: thread -> row r2=tid>>1, chunks cb..cb+1 (cb=(tid&1)*2).
// Swizzle: slot(r,c) holds chunk c^(r&3) (4-chunk space).
// Grid (bm=32, bn=8, z=3) -> XCD = bm%8.
// ---------------------------------------------------------------------------
__global__ __launch_bounds__(256) void gemm_qkv(
    const bf16_t* qb, const bf16_t* kb, const bf16_t* vb, const bf16_t* Wt,
    const float* b0, const float* b1, const float* b2, bf16_t* Qh, bf16_t* Kh,
    bf16_t* Vt) {
  __shared__ bf16_t As[2][128 * 32];
  __shared__ bf16_t Bs[2][128 * 32];
  const int tid = threadIdx.x, w = tid >> 6, lane = tid & 63;
  const int bm = blockIdx.x, bn = blockIdx.y;  // XCD = bm%8
  const int wr = w >> 1, wc = w & 1, q4 = lane >> 4, lo = lane & 15;
  const int z = blockIdx.z;
  const bf16_t* A = (z == 0) ? qb : (z == 1) ? kb : vb;
  const bf16_t* Bt = Wt + (size_t)z * 1024 * 1024;
  const float* bias = (z == 0) ? b0 : (z == 1) ? b1 : b2;

  f32x4 acc[4][4];
#pragma unroll
  for (int m = 0; m < 4; m++)
#pragma unroll
    for (int n = 0; n < 4; n++) acc[m][n] = (f32x4){0.f, 0.f, 0.f, 0.f};

  const int r2 = tid >> 1;         // 0..127
  const int cb = (tid & 1) * 2;    // chunk base 0 / 2 (4 chunks per row)
  const bf16_t* Arow = A + (size_t)(bm * 128 + r2) * 1024;
  const bf16_t* Brow = Bt + (size_t)(bn * 128 + r2) * 1024;

  bf16x8 ar[2], br[2];
  auto loadAB = [&](int k0) {
#pragma unroll
    for (int i = 0; i < 2; i++) {
      ar[i] = *(const bf16x8*)(Arow + k0 + (cb + i) * 8);
      br[i] = *(const bf16x8*)(Brow + k0 + (cb + i) * 8);
    }
  };

  loadAB(0);
  for (int k = 0; k < 32; k++) {
    const int cur = k & 1;
    // deposit tile k (waits only on its own global loads)
#pragma unroll
    for (int i = 0; i < 2; i++) {
      *(bf16x8*)&As[cur][r2 * 32 + (((cb + i) ^ (r2 & 3)) * 8)] = ar[i];
      *(bf16x8*)&Bs[cur][r2 * 32 + (((cb + i) ^ (r2 & 3)) * 8)] = br[i];
    }
    // prefetch tile k+1 into private regs (in flight through barrier+compute)
    if (k < 31) loadAB((k + 1) * 32);
    __syncthreads();

    bf16x8 af[4], bfr[4];
#pragma unroll
    for (int m = 0; m < 4; m++) {
      int rr = wr * 64 + m * 16 + lo;
      af[m] = *(const bf16x8*)&As[cur][rr * 32 + ((q4 ^ (rr & 3)) * 8)];
    }
#pragma unroll
    for (int n = 0; n < 4; n++) {
      int rr = wc * 64 + n * 16 + lo;
      bfr[n] = *(const bf16x8*)&Bs[cur][rr * 32 + ((q4 ^ (rr & 3)) * 8)];
    }
#pragma unroll
    for (int m = 0; m < 4; m++)
#pragma unroll
      for (int n = 0; n < 4; n++)
        acc[m][n] = MFMA16(af[m], bfr[n], acc[m][n]);
    // no trailing barrier: dbuf + top-of-iter deposit make it safe
  }

#pragma unroll
  for (int m = 0; m < 4; m++) {
#pragma unroll
    for (int n = 0; n < 4; n++) {
      int rowg0 = bm * 128 + wr * 64 + m * 16 + q4 * 4;
      int colg = bn * 128 + wc * 64 + n * 16 + lo;
      float bv = bias[colg];
#pragma unroll
      for (int rg = 0; rg < 4; rg++) {
        float val = acc[m][n][rg] + bv;
        int row = rowg0 + rg;
        int b = row >> 11, s = row & 2047;  // S=2048
        int h = colg >> 7, d = colg & 127;  // DH=128
        if (z == 0)
          Qh[(((size_t)(b * 8 + h)) * 2048 + s) * 128 + d] = (bf16_t)val;
        else if (z == 1)
          Kh[(((size_t)(b * 8 + h)) * 2048 + s) * 128 + d] = (bf16_t)val;
        else
          Vt[(((size_t)(b * 8 + h)) * 128 + d) * 2048 + s] = (bf16_t)val;
      }
    }
  }
}

// ---------------------------------------------------------------------------
// gemm_out: BM=64 x BN=128, BK=32 (LDS 24KB -> up to 6 blocks/CU).
// Grid (64, 8) = 512 blocks. 4 waves as 2x2: wave (wr,wc) = rows wr*32..+31
// x cols wc*64..+63. A staging 1 chunk/thread, B staging 2 chunks/thread.
// ---------------------------------------------------------------------------
__global__ __launch_bounds__(256) void gemm_out(const bf16_t* ctx,
                                                const bf16_t* Wt3,
                                                const float* bo, float* Of32) {
  __shared__ bf16_t As[2][64 * 32];
  __shared__ bf16_t Bs[2][128 * 32];
  const int tid = threadIdx.x, w = tid >> 6, lane = tid & 63;
  const int bm = blockIdx.x, bn = blockIdx.y;  // XCD = bm%8
  const int wr = w >> 1, wc = w & 1, q4 = lane >> 4, lo = lane & 15;

  f32x4 acc[2][4];
#pragma unroll
  for (int m = 0; m < 2; m++)
#pragma unroll
    for (int n = 0; n < 4; n++) acc[m][n] = (f32x4){0.f, 0.f, 0.f, 0.f};

  const int ra = tid >> 2;         // 0..63
  const int ca = tid & 3;          // chunk 0..3 (1 chunk/thread)
  const int rb = tid >> 1;         // 0..127
  const int cbb = (tid & 1) * 2;   // chunk base 0 / 2
  const bf16_t* Arow = ctx + (size_t)(bm * 64 + ra) * 1024;
  const bf16_t* Brow = Wt3 + (size_t)(bn * 128 + rb) * 1024;

  bf16x8 ar, br[2];
  auto loadAB = [&](int k0) {
    ar = *(const bf16x8*)(Arow + k0 + ca * 8);
#pragma unroll
    for (int i = 0; i < 2; i++)
      br[i] = *(const bf16x8*)(Brow + k0 + (cbb + i) * 8);
  };

  loadAB(0);
  for (int k = 0; k < 32; k++) {
    const int cur = k & 1;
    *(bf16x8*)&As[cur][ra * 32 + ((ca ^ (ra & 3)) * 8)] = ar;
#pragma unroll
    for (int i = 0; i < 2; i++)
      *(bf16x8*)&Bs[cur][rb * 32 + (((cbb + i) ^ (rb & 3)) * 8)] = br[i];
    if (k < 31) loadAB((k + 1) * 32);
    __syncthreads();

    bf16x8 af[2], bfr[4];
#pragma unroll
    for (int m = 0; m < 2; m++) {
      int rr = wr * 32 + m * 16 + lo;
      af[m] = *(const bf16x8*)&As[cur][rr * 32 + ((q4 ^ (rr & 3)) * 8)];
    }
#pragma unroll
    for (int n = 0; n < 4; n++) {
      int rr = wc * 64 + n * 16 + lo;
      bfr[n] = *(const bf16x8*)&Bs[cur][rr * 32 + ((q4 ^ (rr & 3)) * 8)];
    }
#pragma unroll
    for (int m = 0; m < 2; m++)
#pragma unroll
      for (int n = 0; n < 4; n++)
        acc[m][n] = MFMA16(af[m], bfr[n], acc[m][n]);
  }

#pragma unroll
  for (int m = 0; m < 2; m++) {
#pragma unroll
    for (int n = 0; n < 4; n++) {
      int rowg0 = bm * 64 + wr * 32 + m * 16 + q4 * 4;
      int colg = bn * 128 + wc * 64 + n * 16 + lo;
      float bv = bo[colg];
#pragma unroll
      for (int rg = 0; rg < 4; rg++)
        Of32[(size_t)(rowg0 + rg) * 1024 + colg] = acc[m][n][rg] + bv;
    }
  }
}

// ---------------------------------------------------------------------------
// Flash attention v7 (R13, proven 51.5us): R8 skeleton (512 blocks,
// t/(31-t) pairing, QBLK=64, 4 waves, reg-staged dbuf K/V), key-split
// wave map: wave (r=w>>1, kh=w&1) owns rows r*32..+31 x keys kh*32..+31.
// Ps per-wave [32 rows][stride 40]. End-of-block combine of key-half
// partials via dead staging LDS. NO second launch_bounds arg (R14/R17/R18).
// ---------------------------------------------------------------------------
__global__ __launch_bounds__(256) void flash_k(const bf16_t* Qh,
                                               const bf16_t* Kh,
                                               const bf16_t* Vt, bf16_t* ctx,
                                               const int* causal_p) {
  __shared__ bf16_t sm[32768 + 4 * 1280];
  const int tid = threadIdx.x, w = tid >> 6, lane = tid & 63;
  const int q4 = lane >> 4, lo = lane & 15;
  const int r = w >> 1, kh = w & 1;  // row-group (32 rows), key-half (32 keys)
  const int n0 = blockIdx.x;
  const int u = n0 & 255, hi = n0 >> 8;
  const int bh = u & 15, p0 = u >> 4;
  const int t = hi ? (31 - p0) : p0;
  const int causal = *causal_p;
  const int kmax = causal ? t : 31;

  bf16_t* Ps = sm + 32768 + w * 1280;  // [32 rows][40], 2560B per wave

  // Q fragments: rows t*64 + r*32 + m*16 + lo, dh chunk ks*32 + q4*8.
  bf16x8 aq[2][4];
#pragma unroll
  for (int m = 0; m < 2; m++) {
    const bf16_t* qa =
        Qh + ((size_t)bh * 2048 + t * 64 + r * 32 + m * 16 + lo) * 128;
#pragma unroll
    for (int ks = 0; ks < 4; ks++)
      aq[m][ks] = *(const bf16x8*)(qa + ks * 32 + q4 * 8);
  }

  const bf16_t* Kbase = Kh + (size_t)bh * 2048 * 128;
  const bf16_t* Vbase = Vt + (size_t)bh * 128 * 2048;
  const int kr = tid >> 2, kc = (tid & 3) * 4;
  const int vd = tid >> 1, vc = (tid & 1) * 4;

  bf16x8 kreg[4], vreg[4];
  auto loadKV = [&](int kt) {
    const bf16_t* kp = Kbase + (size_t)(kt * 64 + kr) * 128;
    const bf16_t* vp = Vbase + (size_t)vd * 2048 + kt * 64;
#pragma unroll
    for (int i = 0; i < 4; i++) {
      kreg[i] = *(const bf16x8*)(kp + (kc + i) * 8);
      vreg[i] = *(const bf16x8*)(vp + (vc + i) * 8);
    }
  };

  f32x4 acc[2][8];  // partial over this wave's key-half
  f32x4 lacc[2];
#pragma unroll
  for (int m = 0; m < 2; m++) {
#pragma unroll
    for (int i = 0; i < 8; i++) acc[m][i] = (f32x4){0.f, 0.f, 0.f, 0.f};
    lacc[m] = (f32x4){0.f, 0.f, 0.f, 0.f};
  }

  const bf16_t one = (bf16_t)1.0f;
  const bf16x8 vone = {one, one, one, one, one, one, one, one};
  const float sc2 = 0.08838834764831845f * 1.44269504088896f;

  loadKV(0);
  for (int kt = 0; kt <= kmax; ++kt) {
    bf16_t* Kd = sm + (kt & 1) * 8192;
    bf16_t* Vd = sm + 16384 + (kt & 1) * 8192;
#pragma unroll
    for (int i = 0; i < 4; i++)
      *(bf16x8*)&Kd[kr * 128 + (((kc + i) ^ (kr & 7)) * 8)] = kreg[i];
#pragma unroll
    for (int i = 0; i < 4; i++)
      *(bf16x8*)&Vd[vd * 64 + (((vc + i) ^ ((vd >> 1) & 7)) * 8)] = vreg[i];
    if (kt < kmax) loadKV(kt + 1);
    __syncthreads();

    // ---- QK^T: [32 rows x 32 keys] per wave ----
    f32x4 sa[2][2];
#pragma unroll
    for (int m = 0; m < 2; m++)
#pragma unroll
      for (int nt = 0; nt < 2; nt++) sa[m][nt] = (f32x4){0.f, 0.f, 0.f, 0.f};
#pragma unroll
    for (int ks = 0; ks < 4; ks++) {
#pragma unroll
      for (int nt = 0; nt < 2; nt++) {
        int key = kh * 32 + nt * 16 + lo;
        bf16x8 bk =
            *(const bf16x8*)&Kd[key * 128 + (((ks * 4 + q4) ^ (key & 7)) * 8)];
        sa[0][nt] = MFMA16(aq[0][ks], bk, sa[0][nt]);
        sa[1][nt] = MFMA16(aq[1][ks], bk, sa[1][nt]);
      }
    }

    // ---- softmax numerator -> wave-private P [32 rows x 32 keys] ----
    const bool diag = causal && (kt == t);
#pragma unroll
    for (int m = 0; m < 2; m++) {
#pragma unroll
      for (int nt = 0; nt < 2; nt++) {
        int keyrel = kh * 32 + nt * 16 + lo;  // within 64-key tile
#pragma unroll
        for (int rg = 0; rg < 4; rg++) {
          int rowrel = r * 32 + m * 16 + q4 * 4 + rg;
          float pv = exp2f(sa[m][nt][rg] * sc2);
          if (diag && keyrel > rowrel) pv = 0.f;
          Ps[(m * 16 + q4 * 4 + rg) * 40 + nt * 16 + lo] = (bf16_t)pv;
        }
      }
    }

    // ---- P fragments (K=32 covers the wave's whole key-half) ----
    bf16x8 ap[2];
#pragma unroll
    for (int m = 0; m < 2; m++) {
      ap[m] = *(const bf16x8*)&Ps[(m * 16 + lo) * 40 + q4 * 8];
      lacc[m] = MFMA16(ap[m], vone, lacc[m]);
    }
    // ---- PV partial over keys kh*32..+31 (chunk kh*4+q4 of V rows) ----
#pragma unroll
    for (int n = 0; n < 8; n++) {
      int d = n * 16 + lo;
      int sw = (d >> 1) & 7;
      bf16x8 bv = *(const bf16x8*)&Vd[d * 64 + (((kh * 4 + q4) ^ sw) * 8)];
      acc[0][n] = MFMA16(ap[0], bv, acc[0][n]);
      acc[1][n] = MFMA16(ap[1], bv, acc[1][n]);
    }
  }

  // ---- combine key-half partials (once per block) ----
  __syncthreads();  // staging LDS now dead; Ps reads all done
  float* farena = (float*)sm;  // 8192 floats = 32KB (staging region)
  if (kh == 1) {
    int base = r * 4096 + lane * 64;
#pragma unroll
    for (int m = 0; m < 2; m++)
#pragma unroll
      for (int n = 0; n < 8; n++) {
        int c = m * 8 + n;
        *(f32x4*)&farena[base + ((c ^ (lane & 15)) & 15) * 4] = acc[m][n];
      }
    float* lp = (float*)(sm + 32768 + w * 1280);
    *(f32x4*)&lp[lane * 8] = lacc[0];
    *(f32x4*)&lp[lane * 8 + 4] = lacc[1];
  }
  __syncthreads();
  if (kh == 0) {
    int base = r * 4096 + lane * 64;
    float* lp = (float*)(sm + 32768 + (w + 1) * 1280);
    lacc[0] += *(const f32x4*)&lp[lane * 8];
    lacc[1] += *(const f32x4*)&lp[lane * 8 + 4];
#pragma unroll
    for (int m = 0; m < 2; m++)
#pragma unroll
      for (int n = 0; n < 8; n++) {
        int c = m * 8 + n;
        acc[m][n] += *(const f32x4*)&farena[base + ((c ^ (lane & 15)) & 15) * 4];
      }
    int b = bh >> 3, h = bh & 7;
#pragma unroll
    for (int m = 0; m < 2; m++) {
#pragma unroll
      for (int rg = 0; rg < 4; rg++) {
        float inv = 1.f / lacc[m][rg];
        int row = b * 2048 + t * 64 + r * 32 + m * 16 + q4 * 4 + rg;
#pragma unroll
        for (int n = 0; n < 8; n++)
          ctx[(size_t)row * 1024 + h * 128 + n * 16 + lo] =
              (bf16_t)(acc[m][n][rg] * inv);
      }
    }
  }
}

// ---------------------------------------------------------------------------
extern "C" void kernel_launch(void* const* d_in, const int* in_sizes, int n_in,
                              void* d_out, int out_size, void* d_ws,
                              size_t ws_size, hipStream_t stream) {
  const float* q = (const float*)d_in[0];
  const float* k = (const float*)d_in[1];
  const float* v = (const float*)d_in[2];
  const float* Wq = (const float*)d_in[3];
  const float* bq = (const float*)d_in[4];
  const float* Wk = (const float*)d_in[5];
  const float* bk = (const float*)d_in[6];
  const float* Wv = (const float*)d_in[7];
  const float* bv = (const float*)d_in[8];
  const float* Wo = (const float*)d_in[9];
  const float* bo = (const float*)d_in[10];
  const int* isc = (const int*)d_in[11];

  char* ws = (char*)d_ws;
  bf16_t* Wt = (bf16_t*)ws;                     // 8MB: W^T bf16 x4
  bf16_t* qb = (bf16_t*)(ws + (8ull << 20));    // 8MB
  bf16_t* kb = (bf16_t*)(ws + (16ull << 20));   // 8MB
  bf16_t* vb = (bf16_t*)(ws + (24ull << 20));   // 8MB
  bf16_t* Qh = (bf16_t*)(ws + (32ull << 20));   // 8MB [B,H,S,DH]
  bf16_t* Kh = (bf16_t*)(ws + (40ull << 20));   // 8MB [B,H,S,DH]
  bf16_t* Vt = (bf16_t*)(ws + (48ull << 20));   // 8MB [B,H,DH,S]
  bf16_t* ctx = (bf16_t*)(ws + (8ull << 20));   // reuse qb

  prep<<<dim3(10240), 256, 0, stream>>>(q, k, v, qb, kb, vb, Wq, Wk, Wv, Wo, Wt);

  gemm_qkv<<<dim3(32, 8, 3), 256, 0, stream>>>(qb, kb, vb, Wt, bq, bk, bv, Qh,
                                               Kh, Vt);

  flash_k<<<dim3(512), 256, 0, stream>>>(Qh, Kh, Vt, ctx, isc);

  gemm_out<<<dim3(64, 8), 256, 0, stream>>>(ctx, Wt + 3ull * 1024 * 1024, bo,
                                            (float*)d_out);
}